// Round 12
// baseline (647.176 us; speedup 1.0000x reference)
//
#include <hip/hip_runtime.h>

#define D_DIM 1024
#define NROWS 8192

typedef float f32x4 __attribute__((ext_vector_type(4)));
typedef long  i64x2 __attribute__((ext_vector_type(2)));

typedef const __attribute__((address_space(1))) void* gaddr_t;
typedef __attribute__((address_space(3))) void* laddr_t;

__device__ __forceinline__ void load16_to_lds(const void* g, void* l) {
    __builtin_amdgcn_global_load_lds((gaddr_t)g, (laddr_t)l, 16, 0, 0);
}

// ---- kernel 1: fp32 row-normalize -> fp8 e4m3, one WAVE per row (no barriers).
// K is PERMUTED within each 128-element block (identically for A and B — dot
// products are K-permutation-invariant): orig k = 32s+8f+b (s=step 0..3,
// f=lane quarter 0..3, b=0..7) stored at byte (f + 4*(s>>1))*16 + (s&1)*8 + b.
// Writes stay within their 128-B line -> coalesced. Also zeroes the
// encoded-max array and the gemm completion counter (ws poisoned 0xAA).
__global__ __launch_bounds__(256) void normalize_rows(const float* __restrict__ ex,
                                                      const float* __restrict__ ey,
                                                      unsigned char* __restrict__ Aq,
                                                      unsigned char* __restrict__ Bq,
                                                      int* __restrict__ maxenc,
                                                      int* __restrict__ done) {
    const int wave = threadIdx.x >> 6, lane = threadIdx.x & 63;
    const int r = blockIdx.x * 4 + wave;
    if (lane == 0) maxenc[r] = 0;   // 0 < int-encoding of any (cosine+2.0) > 0
    if (blockIdx.x == 0 && threadIdx.x == 0) *done = 0;

    const float* src;
    unsigned char* dst;
    if (r < NROWS) { src = ex + (size_t)r * D_DIM;           dst = Aq + (size_t)r * D_DIM; }
    else           { src = ey + (size_t)(r - NROWS) * D_DIM; dst = Bq + (size_t)(r - NROWS) * D_DIM; }

    float4 v[4];
    float ss = 0.0f;
    #pragma unroll
    for (int j = 0; j < 4; ++j) {
        v[j] = ((const float4*)src)[lane + 64 * j];
        ss += v[j].x * v[j].x + v[j].y * v[j].y + v[j].z * v[j].z + v[j].w * v[j].w;
    }
    #pragma unroll
    for (int off = 32; off; off >>= 1) ss += __shfl_xor(ss, off, 64);
    float scale = 1.0f / fmaxf(sqrtf(ss), 1e-8f);

    #pragma unroll
    for (int j = 0; j < 4; ++j) {
        int p = (lane + 64 * j) << 2;          // orig byte index of this 4-pack
        int blk = p >> 7, w = p & 127;
        int s = w >> 5, f = (w >> 3) & 3, b = w & 7;
        int q = blk * 128 + (f + ((s >> 1) << 2)) * 16 + (s & 1) * 8 + b;
        int pk = 0;   // v_cvt_pk_fp8_f32: RNE, saturating; |x| <= ~0.3, no overflow
        pk = __builtin_amdgcn_cvt_pk_fp8_f32(v[j].x * scale, v[j].y * scale, pk, false);
        pk = __builtin_amdgcn_cvt_pk_fp8_f32(v[j].z * scale, v[j].w * scale, pk, true);
        ((int*)dst)[q >> 2] = pk;
    }
}

// ---- kernel 2: 128x128-tile fp8 MFMA GEMM (C = A . B^T) with fused row/col max
// AND fused finalize. GEMM body is byte-identical to R10 (97 us, 1414 TF, 64.5%
// of fp8 ceiling): BK=128, 2-barrier K-loop, 32 KB LDS, zero bank conflicts
// (16-B XOR swizzle + K-permutation -> paired ds_read_b128), two half-K passes
// (124 combined VGPR+AGPR -> 4 waves/SIMD), XCD-aware 8x8 supertile swizzle.
// R12: the LAST block (device-scope completion counter; atomicMax results live
// at the LLC coherence point and are read back with no-op atomicAdd(p,0) RMWs
// to dodge stale per-XCD L2) computes both log-prob sums inline — removes the
// third kernel launch (~20 us boundary overhead).
__global__ __launch_bounds__(256, 4) void gemm_max(const unsigned char* __restrict__ A,
                                                   const unsigned char* __restrict__ B,
                                                   int* __restrict__ rowmax,
                                                   int* __restrict__ colmax,
                                                   int* __restrict__ done,
                                                   float* __restrict__ out) {
    __shared__ __align__(16) unsigned char Alds[128 * 128];   // 16 KB
    __shared__ __align__(16) unsigned char Blds[128 * 128];   // 16 KB

    const int bid = blockIdx.x;
    const int sgr = bid >> 6;
    const int bm  = ((sgr & 7) << 3) | ((bid >> 3) & 7);
    const int bn  = ((sgr >> 3) << 3) | (bid & 7);
    const int rowb = bm * 128;
    const int colb = bn * 128;

    const int t    = threadIdx.x;
    const int lane = t & 63;
    const int wave = t >> 6;
    const int wm = (wave & 1) * 64;       // wave row offset within tile
    const int wn = (wave >> 1) * 64;      // wave col offset within tile
    const int fr = lane & 15;             // fragment row/col index
    const int fq = lane >> 4;             // quarter: frag k-bytes 8*fq in each step
    const int pos1 = (fq ^ (fr & 7)) * 16;   // swizzled pos of chunk fq (steps 0,1)

    // staging: thread t stages LDS (row t>>3, pos t&7) <- global chunk (t&7)^(row&7)
    const int srow = t >> 3;
    const int scol = ((t ^ (t >> 3)) & 7) * 16;

    const unsigned char* Ag = A + (size_t)(rowb + srow) * D_DIM + scol;
    const unsigned char* Bg = B + (size_t)(colb + srow) * D_DIM + scol;

    f32x4 acc[4][4] = {};

    for (int kt = 0; kt < D_DIM; kt += 128) {
        #pragma unroll
        for (int i = 0; i < 4; ++i)
            load16_to_lds(Ag + (size_t)i * 32 * D_DIM + kt,
                          (char*)Alds + i * 4096 + wave * 1024);
        #pragma unroll
        for (int i = 0; i < 4; ++i)
            load16_to_lds(Bg + (size_t)i * 32 * D_DIM + kt,
                          (char*)Blds + i * 4096 + wave * 1024);
        __syncthreads();

        #pragma unroll
        for (int h = 0; h < 2; ++h) {
            const int pos = pos1 ^ (h << 6);   // h=0: chunk fq (steps 0,1); h=1: chunk fq+4
            i64x2 af[4];
            #pragma unroll
            for (int i = 0; i < 4; ++i)
                af[i] = *(const i64x2*)(Alds + (wm + i * 16 + fr) * 128 + pos);
            #pragma unroll
            for (int j = 0; j < 4; ++j) {
                i64x2 bf = *(const i64x2*)(Blds + (wn + j * 16 + fr) * 128 + pos);
                #pragma unroll
                for (int i = 0; i < 4; ++i) {
                    acc[i][j] = __builtin_amdgcn_mfma_f32_16x16x32_fp8_fp8(af[i][0], bf[0], acc[i][j], 0, 0, 0);
                    acc[i][j] = __builtin_amdgcn_mfma_f32_16x16x32_fp8_fp8(af[i][1], bf[1], acc[i][j], 0, 0, 0);
                }
            }
        }
        __syncthreads();
    }

    // ---- epilogue: fused max reductions.
    // C/D layout (shape-determined, m89-verified): col = lane&15, row = fq*4 + reg.
    const float SH = 2.0f;   // cosine >= -1 -> v+2 > 0 -> int-ordered float bits

    #pragma unroll
    for (int i = 0; i < 4; ++i) {
        #pragma unroll
        for (int r = 0; r < 4; ++r) {
            float m = fmaxf(fmaxf(acc[i][0][r], acc[i][1][r]),
                            fmaxf(acc[i][2][r], acc[i][3][r]));
            m = fmaxf(m, __shfl_xor(m, 1, 64));   // reduce over the 16 lanes sharing fq
            m = fmaxf(m, __shfl_xor(m, 2, 64));
            m = fmaxf(m, __shfl_xor(m, 4, 64));
            m = fmaxf(m, __shfl_xor(m, 8, 64));
            if (fr == 0) {
                int row = rowb + wm + i * 16 + fq * 4 + r;
                atomicMax(&rowmax[row], __float_as_int(m + SH));
            }
        }
    }
    #pragma unroll
    for (int j = 0; j < 4; ++j) {
        float m = -1e30f;
        #pragma unroll
        for (int i = 0; i < 4; ++i)
            #pragma unroll
            for (int r = 0; r < 4; ++r)
                m = fmaxf(m, acc[i][j][r]);
        m = fmaxf(m, __shfl_xor(m, 16, 64));      // reduce over the 4 quarters
        m = fmaxf(m, __shfl_xor(m, 32, 64));
        if (fq == 0) {
            int col = colb + wn + j * 16 + fr;
            atomicMax(&colmax[col], __float_as_int(m + SH));
        }
    }

    // ---- fused finalize: last block to finish reduces both max arrays.
    __threadfence();                       // order this block's atomicMax before counter
    __shared__ int lastFlag;
    __syncthreads();
    if (t == 0) lastFlag = (atomicAdd(done, 1) == (int)gridDim.x - 1);
    __syncthreads();
    if (lastFlag) {
        float s1 = 0.0f, s2 = 0.0f;        // rowmax[0:8192] | colmax[0:8192] contiguous
        #pragma unroll 4
        for (int i = 0; i < 64; ++i) {
            int idx = t + i * 256;         // i<32 -> rowmax half, i>=32 -> colmax half
            int enc = atomicAdd(&rowmax[idx], 0);   // device-scope coherent read
            float v = __int_as_float(enc) - 2.0f;
            float z = (v - 1.0f) * (1.0f / 0.3f);
            float lp = -0.5f * z * z + 0.2850342711212634f;   // -(log(0.3)+0.5*log(2*pi))
            if (idx < NROWS) s1 += lp; else s2 += lp;
        }
        #pragma unroll
        for (int off = 32; off; off >>= 1) {
            s1 += __shfl_xor(s1, off, 64);
            s2 += __shfl_xor(s2, off, 64);
        }
        __shared__ float w1[4], w2[4];
        if (lane == 0) { w1[wave] = s1; w2[wave] = s2; }
        __syncthreads();
        if (t == 0) {
            out[0] = w1[0] + w1[1] + w1[2] + w1[3];
            out[1] = w2[0] + w2[1] + w2[2] + w2[3];
        }
    }
}

extern "C" void kernel_launch(void* const* d_in, const int* in_sizes, int n_in,
                              void* d_out, int out_size, void* d_ws, size_t ws_size,
                              hipStream_t stream) {
    const float* ex = (const float*)d_in[0];
    const float* ey = (const float*)d_in[1];
    float* out = (float*)d_out;

    char* ws = (char*)d_ws;
    unsigned char* Aq = (unsigned char*)ws;                                   // 8 MB
    unsigned char* Bq = (unsigned char*)(ws + (size_t)NROWS * D_DIM);         // 8 MB
    int* rowmax = (int*)(ws + (size_t)2 * NROWS * D_DIM);                     // 32 KB
    int* colmax = rowmax + NROWS;                                             // 32 KB
    int* done   = colmax + NROWS;                                             // 4 B

    normalize_rows<<<(2 * NROWS) / 4, 256, 0, stream>>>(ex, ey, Aq, Bq, rowmax, done);
    gemm_max<<<64 * 64, 256, 0, stream>>>(Aq, Bq, rowmax, colmax, done, out);
}

// Round 13
// 187.562 us; speedup vs baseline: 3.4505x; 3.4505x over previous
//
#include <hip/hip_runtime.h>

#define D_DIM 1024
#define NROWS 8192

typedef float f32x4 __attribute__((ext_vector_type(4)));
typedef long  i64x2 __attribute__((ext_vector_type(2)));

typedef const __attribute__((address_space(1))) void* gaddr_t;
typedef __attribute__((address_space(3))) void* laddr_t;

__device__ __forceinline__ void load16_to_lds(const void* g, void* l) {
    __builtin_amdgcn_global_load_lds((gaddr_t)g, (laddr_t)l, 16, 0, 0);
}

// ---- kernel 1: fp32 row-normalize -> fp8 e4m3, one WAVE per row (no barriers).
// K is PERMUTED within each 128-element block (identically for A and B — dot
// products are K-permutation-invariant): orig k = 32s+8f+b (s=step 0..3,
// f=lane quarter 0..3, b=0..7) stored at byte (f + 4*(s>>1))*16 + (s&1)*8 + b.
// Writes stay within their 128-B line -> coalesced. Also zeroes the
// encoded-max array and the gemm completion counter (ws poisoned 0xAA).
__global__ __launch_bounds__(256) void normalize_rows(const float* __restrict__ ex,
                                                      const float* __restrict__ ey,
                                                      unsigned char* __restrict__ Aq,
                                                      unsigned char* __restrict__ Bq,
                                                      int* __restrict__ maxenc,
                                                      int* __restrict__ done) {
    const int wave = threadIdx.x >> 6, lane = threadIdx.x & 63;
    const int r = blockIdx.x * 4 + wave;
    if (lane == 0) maxenc[r] = 0;   // 0 < int-encoding of any (cosine+2.0) > 0
    if (blockIdx.x == 0 && threadIdx.x == 0) *done = 0;

    const float* src;
    unsigned char* dst;
    if (r < NROWS) { src = ex + (size_t)r * D_DIM;           dst = Aq + (size_t)r * D_DIM; }
    else           { src = ey + (size_t)(r - NROWS) * D_DIM; dst = Bq + (size_t)(r - NROWS) * D_DIM; }

    float4 v[4];
    float ss = 0.0f;
    #pragma unroll
    for (int j = 0; j < 4; ++j) {
        v[j] = ((const float4*)src)[lane + 64 * j];
        ss += v[j].x * v[j].x + v[j].y * v[j].y + v[j].z * v[j].z + v[j].w * v[j].w;
    }
    #pragma unroll
    for (int off = 32; off; off >>= 1) ss += __shfl_xor(ss, off, 64);
    float scale = 1.0f / fmaxf(sqrtf(ss), 1e-8f);

    #pragma unroll
    for (int j = 0; j < 4; ++j) {
        int p = (lane + 64 * j) << 2;          // orig byte index of this 4-pack
        int blk = p >> 7, w = p & 127;
        int s = w >> 5, f = (w >> 3) & 3, b = w & 7;
        int q = blk * 128 + (f + ((s >> 1) << 2)) * 16 + (s & 1) * 8 + b;
        int pk = 0;   // v_cvt_pk_fp8_f32: RNE, saturating; |x| <= ~0.3, no overflow
        pk = __builtin_amdgcn_cvt_pk_fp8_f32(v[j].x * scale, v[j].y * scale, pk, false);
        pk = __builtin_amdgcn_cvt_pk_fp8_f32(v[j].z * scale, v[j].w * scale, pk, true);
        ((int*)dst)[q >> 2] = pk;
    }
}

// ---- kernel 2: 128x128-tile fp8 MFMA GEMM (C = A . B^T) with fused row/col max
// AND fused finalize. GEMM body byte-identical to R10 (97 us, 1414 TF, 64.5% of
// fp8 ceiling). R13 vs R12: __threadfence() -> __threadfence_block().
// R12's device fence emitted buffer_wbl2 (whole-L2 writeback) from every one of
// 4096 blocks, flushing the staged-tile L2 reuse continuously (gemm 97->580 us,
// all pipes idle). The heavy fence is unnecessary: rowmax/colmax are written
// ONLY via atomicMax, which executes at the LLC coherence point (device-scope,
// m20) and whose completion is tracked by vmcnt — already drained to 0 by
// __syncthreads' pre-barrier waitcnt. __threadfence_block gives the
// compiler-level ordering + waitcnt drain with NO cache ops.
__global__ __launch_bounds__(256, 4) void gemm_max(const unsigned char* __restrict__ A,
                                                   const unsigned char* __restrict__ B,
                                                   int* __restrict__ rowmax,
                                                   int* __restrict__ colmax,
                                                   int* __restrict__ done,
                                                   float* __restrict__ out) {
    __shared__ __align__(16) unsigned char Alds[128 * 128];   // 16 KB
    __shared__ __align__(16) unsigned char Blds[128 * 128];   // 16 KB

    const int bid = blockIdx.x;
    const int sgr = bid >> 6;
    const int bm  = ((sgr & 7) << 3) | ((bid >> 3) & 7);
    const int bn  = ((sgr >> 3) << 3) | (bid & 7);
    const int rowb = bm * 128;
    const int colb = bn * 128;

    const int t    = threadIdx.x;
    const int lane = t & 63;
    const int wave = t >> 6;
    const int wm = (wave & 1) * 64;       // wave row offset within tile
    const int wn = (wave >> 1) * 64;      // wave col offset within tile
    const int fr = lane & 15;             // fragment row/col index
    const int fq = lane >> 4;             // quarter: frag k-bytes 8*fq in each step
    const int pos1 = (fq ^ (fr & 7)) * 16;   // swizzled pos of chunk fq (steps 0,1)

    // staging: thread t stages LDS (row t>>3, pos t&7) <- global chunk (t&7)^(row&7)
    const int srow = t >> 3;
    const int scol = ((t ^ (t >> 3)) & 7) * 16;

    const unsigned char* Ag = A + (size_t)(rowb + srow) * D_DIM + scol;
    const unsigned char* Bg = B + (size_t)(colb + srow) * D_DIM + scol;

    f32x4 acc[4][4] = {};

    for (int kt = 0; kt < D_DIM; kt += 128) {
        #pragma unroll
        for (int i = 0; i < 4; ++i)
            load16_to_lds(Ag + (size_t)i * 32 * D_DIM + kt,
                          (char*)Alds + i * 4096 + wave * 1024);
        #pragma unroll
        for (int i = 0; i < 4; ++i)
            load16_to_lds(Bg + (size_t)i * 32 * D_DIM + kt,
                          (char*)Blds + i * 4096 + wave * 1024);
        __syncthreads();

        #pragma unroll
        for (int h = 0; h < 2; ++h) {
            const int pos = pos1 ^ (h << 6);   // h=0: chunk fq (steps 0,1); h=1: chunk fq+4
            i64x2 af[4];
            #pragma unroll
            for (int i = 0; i < 4; ++i)
                af[i] = *(const i64x2*)(Alds + (wm + i * 16 + fr) * 128 + pos);
            #pragma unroll
            for (int j = 0; j < 4; ++j) {
                i64x2 bf = *(const i64x2*)(Blds + (wn + j * 16 + fr) * 128 + pos);
                #pragma unroll
                for (int i = 0; i < 4; ++i) {
                    acc[i][j] = __builtin_amdgcn_mfma_f32_16x16x32_fp8_fp8(af[i][0], bf[0], acc[i][j], 0, 0, 0);
                    acc[i][j] = __builtin_amdgcn_mfma_f32_16x16x32_fp8_fp8(af[i][1], bf[1], acc[i][j], 0, 0, 0);
                }
            }
        }
        __syncthreads();
    }

    // ---- epilogue: fused max reductions.
    // C/D layout (shape-determined, m89-verified): col = lane&15, row = fq*4 + reg.
    const float SH = 2.0f;   // cosine >= -1 -> v+2 > 0 -> int-ordered float bits

    #pragma unroll
    for (int i = 0; i < 4; ++i) {
        #pragma unroll
        for (int r = 0; r < 4; ++r) {
            float m = fmaxf(fmaxf(acc[i][0][r], acc[i][1][r]),
                            fmaxf(acc[i][2][r], acc[i][3][r]));
            m = fmaxf(m, __shfl_xor(m, 1, 64));   // reduce over the 16 lanes sharing fq
            m = fmaxf(m, __shfl_xor(m, 2, 64));
            m = fmaxf(m, __shfl_xor(m, 4, 64));
            m = fmaxf(m, __shfl_xor(m, 8, 64));
            if (fr == 0) {
                int row = rowb + wm + i * 16 + fq * 4 + r;
                atomicMax(&rowmax[row], __float_as_int(m + SH));
            }
        }
    }
    #pragma unroll
    for (int j = 0; j < 4; ++j) {
        float m = -1e30f;
        #pragma unroll
        for (int i = 0; i < 4; ++i)
            #pragma unroll
            for (int r = 0; r < 4; ++r)
                m = fmaxf(m, acc[i][j][r]);
        m = fmaxf(m, __shfl_xor(m, 16, 64));      // reduce over the 4 quarters
        m = fmaxf(m, __shfl_xor(m, 32, 64));
        if (fq == 0) {
            int col = colb + wn + j * 16 + fr;
            atomicMax(&colmax[col], __float_as_int(m + SH));
        }
    }

    // ---- fused finalize: last block to finish reduces both max arrays.
    // atomicMax ops are device-scope (complete at LLC); __threadfence_block
    // (waitcnt-only) + __syncthreads' vmcnt(0) drain order them before the
    // counter increment — no L2 writeback (R12's mistake).
    __threadfence_block();
    __shared__ int lastFlag;
    __syncthreads();
    if (t == 0) lastFlag = (atomicAdd(done, 1) == (int)gridDim.x - 1);
    __syncthreads();
    if (lastFlag) {
        float s1 = 0.0f, s2 = 0.0f;        // rowmax[0:8192] | colmax[0:8192] contiguous
        #pragma unroll 4
        for (int i = 0; i < 64; ++i) {
            int idx = t + i * 256;         // i<32 -> rowmax half, i>=32 -> colmax half
            int enc = atomicAdd(&rowmax[idx], 0);   // device-scope coherent read (LLC RMW)
            float v = __int_as_float(enc) - 2.0f;
            float z = (v - 1.0f) * (1.0f / 0.3f);
            float lp = -0.5f * z * z + 0.2850342711212634f;   // -(log(0.3)+0.5*log(2*pi))
            if (idx < NROWS) s1 += lp; else s2 += lp;
        }
        #pragma unroll
        for (int off = 32; off; off >>= 1) {
            s1 += __shfl_xor(s1, off, 64);
            s2 += __shfl_xor(s2, off, 64);
        }
        __shared__ float w1[4], w2[4];
        if (lane == 0) { w1[wave] = s1; w2[wave] = s2; }
        __syncthreads();
        if (t == 0) {
            out[0] = w1[0] + w1[1] + w1[2] + w1[3];
            out[1] = w2[0] + w2[1] + w2[2] + w2[3];
        }
    }
}

extern "C" void kernel_launch(void* const* d_in, const int* in_sizes, int n_in,
                              void* d_out, int out_size, void* d_ws, size_t ws_size,
                              hipStream_t stream) {
    const float* ex = (const float*)d_in[0];
    const float* ey = (const float*)d_in[1];
    float* out = (float*)d_out;

    char* ws = (char*)d_ws;
    unsigned char* Aq = (unsigned char*)ws;                                   // 8 MB
    unsigned char* Bq = (unsigned char*)(ws + (size_t)NROWS * D_DIM);         // 8 MB
    int* rowmax = (int*)(ws + (size_t)2 * NROWS * D_DIM);                     // 32 KB
    int* colmax = rowmax + NROWS;                                             // 32 KB
    int* done   = colmax + NROWS;                                             // 4 B

    normalize_rows<<<(2 * NROWS) / 4, 256, 0, stream>>>(ex, ey, Aq, Bq, rowmax, done);
    gemm_max<<<64 * 64, 256, 0, stream>>>(Aq, Bq, rowmax, colmax, done, out);
}